// Round 7
// baseline (471.555 us; speedup 1.0000x reference)
//
#include <hip/hip_runtime.h>

// CircuitModel: sequential Oja/Hebbian plasticity scan.
//   y_t = sigmoid(w_t.x_t); w_{t+1} = b_t*w_t + a_t*x_t,
//   a_t = lr*th0*y_t, b_t = 1 + lr*th1*y_t^2; out[t,p] = y_t at observed rows.
//
// R1: __shfl_xor = LDS swizzle ~120cy/step -> DPP reduce.
// R2: readlane is int(int,int) — must bitcast.
// R3-R6: every register-resident prefetch pipeline (depth-8 rotation, slot
//     rotation, ping-pong dbuf + launch_bounds(256,1)) was collapsed by the
//     compiler (VGPR_Count 56/84/88 vs needed 160+); loads sunk to uses;
//     scan pinned at 311-337us = blended VMEM load-to-use latency.
// R7: LDS staging via __builtin_amdgcn_global_load_lds + barrier pipeline.
//     DMA is side-effecting: cannot sink past may-aliasing ds_reads, cannot
//     hoist over __syncthreads -> issue point structurally one full block
//     (~800cy) before the barrier that drains it. 4 waves/workgroup share
//     the staged X rows (4x traffic cut). Band staged in LDS too.

constexpr int N_IN    = 512;
constexpr int T       = 2048;
constexpr int N_OBS   = 256;
constexpr int D       = 8;            // linearization block size
constexpr int NBLK    = T / D;        // 256
constexpr int BANDPAD = 64;           // packed-band floats per block (28 used)
constexpr int ROWB    = N_IN * 4;     // 2048 B per x row
constexpr int BUFB    = D * ROWB + BANDPAD * 4;  // 16640 B per LDS buffer

// Packed band layout for block b (t0=8b): entry k = x_{t0+i}.x_{t0+i+j},
// k = BOFF[i] + (j-1), i=0..6, j=1..7-i (28 entries).
__device__ constexpr int BOFF[8] = {0, 7, 13, 18, 22, 25, 27, 28};

// DPP add-reduce step; old=0 is the additive identity for invalid lanes.
#define DPP_ADD(v, ctrl, rmask)                                                \
    v += __int_as_float(__builtin_amdgcn_update_dpp(                           \
        0, __float_as_int(v), (ctrl), (rmask), 0xf, false))

__device__ __forceinline__ float wave64_sum_bcast(float v) {
    DPP_ADD(v, 0x111, 0xf); // row_shr:1
    DPP_ADD(v, 0x112, 0xf); // row_shr:2
    DPP_ADD(v, 0x114, 0xf); // row_shr:4
    DPP_ADD(v, 0x118, 0xf); // row_shr:8
    DPP_ADD(v, 0x142, 0xa); // row_bcast:15
    DPP_ADD(v, 0x143, 0xc); // row_bcast:31 -> lane63 = total
    return __int_as_float(__builtin_amdgcn_readlane(__float_as_int(v), 63));
}

__device__ __forceinline__ float dot8(const float4& u0, const float4& u1,
                                      const float4& v0, const float4& v1) {
    float p0 = fmaf(u0.x, v0.x, u0.y * v0.y);
    float p1 = fmaf(u0.z, v0.z, u0.w * v0.w);
    float p2 = fmaf(u1.x, v1.x, u1.y * v1.y);
    float p3 = fmaf(u1.z, v1.z, u1.w * v1.w);
    return (p0 + p1) + (p2 + p3);
}

// Async global->LDS DMA. LDS dest = wave-uniform base + lane*size (m104/m108).
typedef __attribute__((address_space(3))) void       lds_t;
typedef const __attribute__((address_space(1))) void gbl_t;
__device__ __forceinline__ void dma16(const float* g, void* l) {
    __builtin_amdgcn_global_load_lds((gbl_t*)g, (lds_t*)l, 16, 0, 0);
}
__device__ __forceinline__ void dma4(const float* g, void* l) {
    __builtin_amdgcn_global_load_lds((gbl_t*)g, (lds_t*)l, 4, 0, 0);
}

// ---- Kernel 1: packed Gram band, one wave per 8-step block -----------------
__global__ __launch_bounds__(64) void gram_kernel(const float* __restrict__ X,
                                                  float* __restrict__ P) {
    const int b    = blockIdx.x;          // 0..NBLK-1, one CU each
    const int lane = threadIdx.x;         // 0..63
    const int t0   = b * D;
    const float4* Xv = (const float4*)(X + (long)t0 * N_IN);
    float4 r[8][2];
    #pragma unroll
    for (int i = 0; i < 8; ++i) {
        r[i][0] = Xv[i * (N_IN / 4) + lane * 2 + 0];
        r[i][1] = Xv[i * (N_IN / 4) + lane * 2 + 1];
    }
    float s[28];
    #pragma unroll
    for (int i = 0; i < 7; ++i) {
        #pragma unroll
        for (int j = 1; j <= 7 - i; ++j) {
            s[BOFF[i] + j - 1] =
                wave64_sum_bcast(dot8(r[i][0], r[i][1], r[i + j][0], r[i + j][1]));
        }
    }
    if (lane == 0) {
        #pragma unroll
        for (int k = 0; k < 28; ++k) P[b * BANDPAD + k] = s[k];
    }
}

// ---- Kernel 2: the scan ----------------------------------------------------
__global__ __launch_bounds__(256, 1) void oja_scan_kernel(
    const float* __restrict__ X,     // [T, N_IN]
    const float* __restrict__ Winit, // [N_OUT, N_IN]
    const float* __restrict__ theta, // [2]
    const int*   __restrict__ obs,   // [N_OBS]
    const float* __restrict__ P,     // [NBLK, BANDPAD] packed band (d_ws)
    float*       __restrict__ out)   // [T, N_OBS]
{
    __shared__ char lds[2 * BUFB];   // 33280 B: two staging buffers

    const int tid  = threadIdx.x;
    const int wid  = tid >> 6;            // 0..3
    const int lane = tid & 63;
    const int wave = blockIdx.x * 4 + wid; // observed-row index; always < 256

    const int row = obs[wave];
    const float lr  = 1.0f / (float)N_IN;
    const float th0 = theta[0] * lr;
    const float th1 = theta[1] * lr;

    const float4* Wv = (const float4*)(Winit + (long)row * N_IN);
    float4 w0 = Wv[lane * 2 + 0];
    float4 w1 = Wv[lane * 2 + 1];

    // Stage block `blk` into buffer `buf`. Wave wid stages rows 2wid,2wid+1
    // (2 chunks of 1KB each: 64 lanes x 16B); wave 3 also stages the band.
    auto stage = [&](int buf, int blk) {
        const int t0b = blk * D;
        char* base = lds + buf * BUFB;
        #pragma unroll
        for (int r = 2 * wid; r < 2 * wid + 2; ++r) {
            const float* g = X + (long)(t0b + r) * N_IN + lane * 4;
            dma16(g,                 base + r * ROWB + 0);
            dma16(g + 256,           base + r * ROWB + 1024);
        }
        if (wid == 3)
            dma4(P + blk * BANDPAD + lane, base + D * ROWB);
    };

    stage(0, 0);   // prologue: block 0 into buffer 0 (drained by first barrier)

    for (int blk = 0; blk < NBLK; ++blk) {
        const int p = blk & 1;
        __syncthreads();   // vmcnt(0)+barrier: buffer p's DMAs (issued one
                           // full block ago) complete & visible to all waves

        // Issue next block's DMAs into the other buffer (pinned here: can't
        // hoist above the barrier, can't sink past may-aliasing ds_reads).
        const int bn = (blk + 1 < NBLK) ? (blk + 1) : blk;
        stage(1 - p, bn);

        // LDS -> registers: this wave's 32B slice of each row + band entry.
        const char* bb = lds + p * BUFB;
        float4 xr[D][2];
        #pragma unroll
        for (int r = 0; r < D; ++r) {
            xr[r][0] = *(const float4*)(bb + r * ROWB + lane * 32);
            xr[r][1] = *(const float4*)(bb + r * ROWB + lane * 32 + 16);
        }
        const float band = *(const float*)(bb + D * ROWB + lane * 4);

        // Boundary: Q_d = w_{t0} . x_{t0+d} (8 independent DPP chains).
        float q[D];
        #pragma unroll
        for (int d = 0; d < D; ++d)
            q[d] = wave64_sum_bcast(dot8(w0, w1, xr[d][0], xr[d][1]));

        // Eight steps: sigmoid + Q propagation + rank-1 w update.
        const int t0 = blk * D;
        float z = q[0];
        #pragma unroll
        for (int i = 0; i < D; ++i) {
            const float y = __builtin_amdgcn_rcpf(1.0f + __expf(-z));
            if (lane == 0) out[(t0 + i) * N_OBS + wave] = y;

            const float a = th0 * y;
            const float b = fmaf(th1 * y, y, 1.0f);

            #pragma unroll
            for (int d = i + 1; d < D; ++d) {
                const int kk = BOFF[i] + (d - i) - 1;
                const float s = __int_as_float(
                    __builtin_amdgcn_readlane(__float_as_int(band), kk));
                q[d] = fmaf(b, q[d], a * s);
            }
            if (i < D - 1) z = q[i + 1];

            w0.x = fmaf(b, w0.x, a * xr[i][0].x);
            w0.y = fmaf(b, w0.y, a * xr[i][0].y);
            w0.z = fmaf(b, w0.z, a * xr[i][0].z);
            w0.w = fmaf(b, w0.w, a * xr[i][0].w);
            w1.x = fmaf(b, w1.x, a * xr[i][1].x);
            w1.y = fmaf(b, w1.y, a * xr[i][1].y);
            w1.z = fmaf(b, w1.z, a * xr[i][1].z);
            w1.w = fmaf(b, w1.w, a * xr[i][1].w);
        }
    }
}

extern "C" void kernel_launch(void* const* d_in, const int* in_sizes, int n_in,
                              void* d_out, int out_size, void* d_ws, size_t ws_size,
                              hipStream_t stream) {
    const float* X     = (const float*)d_in[0];
    const float* Winit = (const float*)d_in[1];
    const float* theta = (const float*)d_in[2];
    const int*   obs   = (const int*)d_in[3];
    float*       out   = (float*)d_out;
    float*       P     = (float*)d_ws;   // NBLK*BANDPAD floats = 64 KB

    // Gram band: one wave per block, spread across 256 CUs.
    gram_kernel<<<NBLK, 64, 0, stream>>>(X, P);

    // Scan: 64 workgroups x 4 waves (one observed row per wave).
    oja_scan_kernel<<<64, 256, 0, stream>>>(X, Winit, theta, obs, P, out);
}

// Round 8
// 444.500 us; speedup vs baseline: 1.0609x; 1.0609x over previous
//
#include <hip/hip_runtime.h>

// CircuitModel: sequential Oja/Hebbian plasticity scan.
//   y_t = sigmoid(w_t.x_t); w_{t+1} = b_t*w_t + a_t*x_t,
//   a_t = lr*th0*y_t, b_t = 1 + lr*th1*y_t^2; out[t,p] = y_t at observed rows.
//
// R1: __shfl_xor = LDS swizzle ~120cy/step -> DPP reduce.
// R2: readlane is int(int,int) — must bitcast.
// R3-R6: register prefetch pipelines all collapsed by regalloc/scheduler;
//     scan pinned at ~311-337us = VMEM load-to-use latency.
// R7: global_load_lds + barrier ping-pong pipeline WORKED structurally
//     (DMA issue pinned a full block ahead) but ds_read at lane*32 B
//     = 16-way bank conflicts (SQ_LDS_BANK_CONFLICT=4.19M); LDS pipe is
//     per-CU shared by 4 waves -> pipe-bound at ~3900cy/block. 418us.
// R8: ownership permutation. Lane i owns row elements [4i,4i+4) and
//     [256+4i,256+4i+4): ds_read_b128 at lane*16 in each half-row =
//     canonical contiguous conflict-free pattern (~12cy, m134). W loads
//     become Wv[lane], Wv[64+lane] (still coalesced). Gram unchanged
//     (dot sums all elements; ownership is irrelevant there).

constexpr int N_IN    = 512;
constexpr int T       = 2048;
constexpr int N_OBS   = 256;
constexpr int D       = 8;            // linearization block size
constexpr int NBLK    = T / D;        // 256
constexpr int BANDPAD = 64;           // packed-band floats per block (28 used)
constexpr int ROWB    = N_IN * 4;     // 2048 B per x row
constexpr int BUFB    = D * ROWB + BANDPAD * 4;  // 16640 B per LDS buffer

// Packed band layout for block b (t0=8b): entry k = x_{t0+i}.x_{t0+i+j},
// k = BOFF[i] + (j-1), i=0..6, j=1..7-i (28 entries).
__device__ constexpr int BOFF[8] = {0, 7, 13, 18, 22, 25, 27, 28};

// DPP add-reduce step; old=0 is the additive identity for invalid lanes.
#define DPP_ADD(v, ctrl, rmask)                                                \
    v += __int_as_float(__builtin_amdgcn_update_dpp(                           \
        0, __float_as_int(v), (ctrl), (rmask), 0xf, false))

__device__ __forceinline__ float wave64_sum_bcast(float v) {
    DPP_ADD(v, 0x111, 0xf); // row_shr:1
    DPP_ADD(v, 0x112, 0xf); // row_shr:2
    DPP_ADD(v, 0x114, 0xf); // row_shr:4
    DPP_ADD(v, 0x118, 0xf); // row_shr:8
    DPP_ADD(v, 0x142, 0xa); // row_bcast:15
    DPP_ADD(v, 0x143, 0xc); // row_bcast:31 -> lane63 = total
    return __int_as_float(__builtin_amdgcn_readlane(__float_as_int(v), 63));
}

__device__ __forceinline__ float dot8(const float4& u0, const float4& u1,
                                      const float4& v0, const float4& v1) {
    float p0 = fmaf(u0.x, v0.x, u0.y * v0.y);
    float p1 = fmaf(u0.z, v0.z, u0.w * v0.w);
    float p2 = fmaf(u1.x, v1.x, u1.y * v1.y);
    float p3 = fmaf(u1.z, v1.z, u1.w * v1.w);
    return (p0 + p1) + (p2 + p3);
}

// Async global->LDS DMA. LDS dest = wave-uniform base + lane*size (m104/m108).
typedef __attribute__((address_space(3))) void       lds_t;
typedef const __attribute__((address_space(1))) void gbl_t;
__device__ __forceinline__ void dma16(const float* g, void* l) {
    __builtin_amdgcn_global_load_lds((gbl_t*)g, (lds_t*)l, 16, 0, 0);
}
__device__ __forceinline__ void dma4(const float* g, void* l) {
    __builtin_amdgcn_global_load_lds((gbl_t*)g, (lds_t*)l, 4, 0, 0);
}

// ---- Kernel 1: packed Gram band, one wave per 8-step block -----------------
__global__ __launch_bounds__(64) void gram_kernel(const float* __restrict__ X,
                                                  float* __restrict__ P) {
    const int b    = blockIdx.x;          // 0..NBLK-1
    const int lane = threadIdx.x;         // 0..63
    const int t0   = b * D;
    const float4* Xv = (const float4*)(X + (long)t0 * N_IN);
    float4 r[8][2];
    #pragma unroll
    for (int i = 0; i < 8; ++i) {
        r[i][0] = Xv[i * (N_IN / 4) + lane * 2 + 0];
        r[i][1] = Xv[i * (N_IN / 4) + lane * 2 + 1];
    }
    float s[28];
    #pragma unroll
    for (int i = 0; i < 7; ++i) {
        #pragma unroll
        for (int j = 1; j <= 7 - i; ++j) {
            s[BOFF[i] + j - 1] =
                wave64_sum_bcast(dot8(r[i][0], r[i][1], r[i + j][0], r[i + j][1]));
        }
    }
    if (lane == 0) {
        #pragma unroll
        for (int k = 0; k < 28; ++k) P[b * BANDPAD + k] = s[k];
    }
}

// ---- Kernel 2: the scan ----------------------------------------------------
__global__ __launch_bounds__(256, 1) void oja_scan_kernel(
    const float* __restrict__ X,     // [T, N_IN]
    const float* __restrict__ Winit, // [N_OUT, N_IN]
    const float* __restrict__ theta, // [2]
    const int*   __restrict__ obs,   // [N_OBS]
    const float* __restrict__ P,     // [NBLK, BANDPAD] packed band (d_ws)
    float*       __restrict__ out)   // [T, N_OBS]
{
    __shared__ char lds[2 * BUFB];   // 33280 B: two staging buffers

    const int tid  = threadIdx.x;
    const int wid  = tid >> 6;            // 0..3
    const int lane = tid & 63;
    const int wave = blockIdx.x * 4 + wid; // observed-row index; always < 256

    const int row = obs[wave];
    const float lr  = 1.0f / (float)N_IN;
    const float th0 = theta[0] * lr;
    const float th1 = theta[1] * lr;

    // Ownership permutation (R8): lane owns elements [4*lane,4*lane+4) and
    // [256+4*lane,256+4*lane+4) — matches conflict-free lane*16 ds_reads.
    const float4* Wv = (const float4*)(Winit + (long)row * N_IN);
    float4 w0 = Wv[lane];
    float4 w1 = Wv[64 + lane];

    // Stage block `blk` into buffer `buf`. Wave wid stages rows 2wid,2wid+1
    // (2 chunks of 1KB each: 64 lanes x 16B); wave 3 also stages the band.
    auto stage = [&](int buf, int blk) {
        const int t0b = blk * D;
        char* base = lds + buf * BUFB;
        #pragma unroll
        for (int r = 2 * wid; r < 2 * wid + 2; ++r) {
            const float* g = X + (long)(t0b + r) * N_IN + lane * 4;
            dma16(g,                 base + r * ROWB + 0);
            dma16(g + 256,           base + r * ROWB + 1024);
        }
        if (wid == 3)
            dma4(P + blk * BANDPAD + lane, base + D * ROWB);
    };

    stage(0, 0);   // prologue: block 0 into buffer 0 (drained by first barrier)

    for (int blk = 0; blk < NBLK; ++blk) {
        const int p = blk & 1;
        __syncthreads();   // vmcnt(0)+barrier: buffer p's DMAs (issued one
                           // full block ago) complete & visible to all waves

        // Issue next block's DMAs into the other buffer (pinned here: can't
        // hoist above the barrier, can't sink past may-aliasing ds_reads).
        const int bn = (blk + 1 < NBLK) ? (blk + 1) : blk;
        stage(1 - p, bn);

        // LDS -> registers, conflict-free: lane*16 within each half-row.
        const char* bb = lds + p * BUFB;
        float4 xr[D][2];
        #pragma unroll
        for (int r = 0; r < D; ++r) {
            xr[r][0] = *(const float4*)(bb + r * ROWB + lane * 16);
            xr[r][1] = *(const float4*)(bb + r * ROWB + 1024 + lane * 16);
        }
        const float band = *(const float*)(bb + D * ROWB + lane * 4);

        // Boundary: Q_d = w_{t0} . x_{t0+d} (8 independent DPP chains).
        float q[D];
        #pragma unroll
        for (int d = 0; d < D; ++d)
            q[d] = wave64_sum_bcast(dot8(w0, w1, xr[d][0], xr[d][1]));

        // Eight steps: sigmoid + Q propagation + rank-1 w update.
        const int t0 = blk * D;
        float z = q[0];
        #pragma unroll
        for (int i = 0; i < D; ++i) {
            const float y = __builtin_amdgcn_rcpf(1.0f + __expf(-z));
            if (lane == 0) out[(t0 + i) * N_OBS + wave] = y;

            const float a = th0 * y;
            const float b = fmaf(th1 * y, y, 1.0f);

            #pragma unroll
            for (int d = i + 1; d < D; ++d) {
                const int kk = BOFF[i] + (d - i) - 1;
                const float s = __int_as_float(
                    __builtin_amdgcn_readlane(__float_as_int(band), kk));
                q[d] = fmaf(b, q[d], a * s);
            }
            if (i < D - 1) z = q[i + 1];

            w0.x = fmaf(b, w0.x, a * xr[i][0].x);
            w0.y = fmaf(b, w0.y, a * xr[i][0].y);
            w0.z = fmaf(b, w0.z, a * xr[i][0].z);
            w0.w = fmaf(b, w0.w, a * xr[i][0].w);
            w1.x = fmaf(b, w1.x, a * xr[i][1].x);
            w1.y = fmaf(b, w1.y, a * xr[i][1].y);
            w1.z = fmaf(b, w1.z, a * xr[i][1].z);
            w1.w = fmaf(b, w1.w, a * xr[i][1].w);
        }
    }
}

extern "C" void kernel_launch(void* const* d_in, const int* in_sizes, int n_in,
                              void* d_out, int out_size, void* d_ws, size_t ws_size,
                              hipStream_t stream) {
    const float* X     = (const float*)d_in[0];
    const float* Winit = (const float*)d_in[1];
    const float* theta = (const float*)d_in[2];
    const int*   obs   = (const int*)d_in[3];
    float*       out   = (float*)d_out;
    float*       P     = (float*)d_ws;   // NBLK*BANDPAD floats = 64 KB

    // Gram band: one wave per block, spread across CUs.
    gram_kernel<<<NBLK, 64, 0, stream>>>(X, P);

    // Scan: 64 workgroups x 4 waves (one observed row per wave).
    oja_scan_kernel<<<64, 256, 0, stream>>>(X, Winit, theta, obs, P, out);
}